// Round 3
// baseline (348.900 us; speedup 1.0000x reference)
//
#include <hip/hip_runtime.h>
#include <hip/hip_bf16.h>
#include <math.h>

// Problem constants (fixed by the reference file)
#define T_TOK 2048
#define H_DIM 1024
#define I_DIM 2048
#define E_NUM 8
#define TOPK  2
#define P_MAX (T_TOK * TOPK)   // 4096 (token, k) pairs
#define MAX_SLOTS 40           // sum_e ceil(M_e/128) <= 32 + 7 = 39

typedef __bf16 bf16_t;
typedef __attribute__((ext_vector_type(8))) __bf16 bf16x8;
typedef __attribute__((ext_vector_type(4))) float  f32x4;

__device__ inline f32x4 zero4() {
    f32x4 z; z[0] = 0.f; z[1] = 0.f; z[2] = 0.f; z[3] = 0.f; return z;
}

__device__ inline bf16x8 cvt8(f32x4 a, f32x4 b) {
    bf16x8 o;
    o[0] = (bf16_t)a[0]; o[1] = (bf16_t)a[1]; o[2] = (bf16_t)a[2]; o[3] = (bf16_t)a[3];
    o[4] = (bf16_t)b[0]; o[5] = (bf16_t)b[1]; o[6] = (bf16_t)b[2]; o[7] = (bf16_t)b[3];
    return o;
}

__device__ inline bf16x8 zero8bf() {
    bf16x8 o;
    #pragma unroll
    for (int z = 0; z < 8; z++) o[z] = (bf16_t)0.f;
    return o;
}

// ---------------------------------------------------------------- init
__global__ void init_kernel(int* counts, int* cursor) {
    int i = threadIdx.x;
    if (i < E_NUM) { counts[i] = 0; cursor[i] = 0; }
}

// ---------------------------------------------------------------- router
__global__ void router_kernel(const float* __restrict__ gating,
                              int* __restrict__ expert_id,
                              float* __restrict__ wt,
                              int* __restrict__ counts) {
    int t = blockIdx.x * blockDim.x + threadIdx.x;
    if (t >= T_TOK) return;
    float l[E_NUM];
    float m = -1e30f;
    #pragma unroll
    for (int e = 0; e < E_NUM; e++) { l[e] = gating[t * E_NUM + e]; m = fmaxf(m, l[e]); }
    float p[E_NUM];
    #pragma unroll
    for (int e = 0; e < E_NUM; e++) p[e] = __expf(l[e] - m);
    int i0 = 0; float p0 = p[0];
    #pragma unroll
    for (int e = 1; e < E_NUM; e++) if (p[e] > p0) { p0 = p[e]; i0 = e; }
    int i1 = -1; float p1 = -1.f;
    #pragma unroll
    for (int e = 0; e < E_NUM; e++) if (e != i0 && p[e] > p1) { p1 = p[e]; i1 = e; }
    float inv = 1.f / (p0 + p1);
    expert_id[t * 2 + 0] = i0; wt[t * 2 + 0] = p0 * inv;
    expert_id[t * 2 + 1] = i1; wt[t * 2 + 1] = p1 * inv;
    atomicAdd(&counts[i0], 1);
    atomicAdd(&counts[i1], 1);
}

// ---------------------------------------------------------------- scan + tile map
__global__ void scan_kernel(const int* __restrict__ counts,
                            int* __restrict__ offsets,
                            int* __restrict__ tile_e, int* __restrict__ tile_m0,
                            int* __restrict__ n_slots) {
    if (threadIdx.x != 0 || blockIdx.x != 0) return;
    int off = 0;
    for (int e = 0; e < E_NUM; e++) { offsets[e] = off; off += counts[e]; }
    offsets[E_NUM] = off;
    int s = 0;
    for (int e = 0; e < E_NUM; e++)
        for (int m0 = offsets[e]; m0 < offsets[e + 1]; m0 += 128) {
            tile_e[s] = e; tile_m0[s] = m0; s++;
        }
    *n_slots = s;
}

// ---------------------------------------------------------------- scatter
__global__ void scatter_kernel(const int* __restrict__ expert_id,
                               const float* __restrict__ wt,
                               const int* __restrict__ offsets,
                               int* __restrict__ cursor,
                               int* __restrict__ pair_token,
                               int* __restrict__ pair_dst,
                               float* __restrict__ pair_wt) {
    int t = blockIdx.x * blockDim.x + threadIdx.x;
    if (t >= T_TOK) return;
    #pragma unroll
    for (int k = 0; k < TOPK; k++) {
        int e = expert_id[t * 2 + k];
        int p = offsets[e] + atomicAdd(&cursor[e], 1);
        pair_token[p] = t;
        pair_dst[p]   = t * 2 + k;
        pair_wt[p]    = wt[t * 2 + k];
    }
}

// ---------------------------------------------------------------- GEMM1 + SwiGLU
// Block: 128 rows x 128 act-cols. B tile = 256 w1 rows (128 gate + 128 up).
// BK=64 (128 B LDS rows), XOR-swizzled 16B granules: slot = g ^ (row&7).
// 4 waves 2x2; wave = 64 rows x 64 act cols; acc[4][8] (gate j=0..3, up j=4..7);
// 64 MFMA per wave per K-step.
__global__ __launch_bounds__(256)
void gemm1_kernel(const float* __restrict__ hidden,
                  const float* __restrict__ w1,
                  const int* __restrict__ pair_token,
                  const int* __restrict__ offsets,
                  const int* __restrict__ tile_e,
                  const int* __restrict__ tile_m0,
                  const int* __restrict__ n_slots,
                  bf16_t* __restrict__ act) {
    int slot = blockIdx.x;
    if (slot >= *n_slots) return;
    int e    = tile_e[slot];
    int m0   = tile_m0[slot];
    int mend = offsets[e + 1];
    int c0   = blockIdx.y * 128;  // act cols [c0, c0+128)
    const float* w1e = w1 + (size_t)e * (2 * I_DIM) * H_DIM;

    __shared__ __align__(16) unsigned char smem[128 * 128 + 256 * 128]; // 48 KB
    unsigned char* sA = smem;             // 128 rows x 128 B
    unsigned char* sB = smem + 128 * 128; // 256 rows x 128 B (gate rows 0..127, up 128..255)

    int tid = threadIdx.x;
    // A staging: 2 threads per row, 32 f32 (4 granules) each
    int ar = tid >> 1, ah = tid & 1;
    int tok = -1;
    if (m0 + ar < mend) tok = pair_token[m0 + ar];
    const float* aSrc = hidden + (size_t)(tok < 0 ? 0 : tok) * H_DIM + ah * 32;
    int aswz = ar & 7;
    // B staging: 1 thread per row, 64 f32 (8 granules) each
    int brs = tid;
    int w1row = (brs < 128) ? (c0 + brs) : (I_DIM + c0 + (brs - 128));
    const float* bSrc = w1e + (size_t)w1row * H_DIM;
    int bswz = brs & 7;

    int lane = tid & 63, wid = tid >> 6;
    int wm = wid >> 1, wn = wid & 1;
    int l15 = lane & 15, l7 = lane & 7, lg = lane >> 4;

    f32x4 acc[4][8];
    #pragma unroll
    for (int i = 0; i < 4; i++)
        #pragma unroll
        for (int j = 0; j < 8; j++) acc[i][j] = zero4();

    for (int k0 = 0; k0 < H_DIM; k0 += 64) {
        __syncthreads();
        {   // stage A
            const f32x4* s = (const f32x4*)(aSrc + k0);
            #pragma unroll
            for (int q = 0; q < 4; q++) {
                f32x4 v0 = zero4(), v1 = zero4();
                if (tok >= 0) { v0 = s[q * 2]; v1 = s[q * 2 + 1]; }
                int g = ah * 4 + q;
                *(bf16x8*)(sA + ar * 128 + ((g ^ aswz) << 4)) = cvt8(v0, v1);
            }
        }
        {   // stage B
            const f32x4* s = (const f32x4*)(bSrc + k0);
            #pragma unroll
            for (int g = 0; g < 8; g++) {
                f32x4 v0 = s[g * 2], v1 = s[g * 2 + 1];
                *(bf16x8*)(sB + brs * 128 + ((g ^ bswz) << 4)) = cvt8(v0, v1);
            }
        }
        __syncthreads();

        #pragma unroll
        for (int kh = 0; kh < 2; kh++) {
            int slotg = (((kh * 4 + lg) ^ l7) << 4);
            bf16x8 a[4], bg[4], bu[4];
            #pragma unroll
            for (int i = 0; i < 4; i++) {
                int row = wm * 64 + i * 16 + l15;
                a[i] = *(const bf16x8*)(sA + row * 128 + slotg);
            }
            #pragma unroll
            for (int j = 0; j < 4; j++) {
                int rowg = wn * 64 + j * 16 + l15;
                bg[j] = *(const bf16x8*)(sB + rowg * 128 + slotg);
                bu[j] = *(const bf16x8*)(sB + (128 + rowg) * 128 + slotg);
            }
            #pragma unroll
            for (int i = 0; i < 4; i++)
                #pragma unroll
                for (int j = 0; j < 4; j++) {
                    acc[i][j]     = __builtin_amdgcn_mfma_f32_16x16x32_bf16(a[i], bg[j], acc[i][j], 0, 0, 0);
                    acc[i][j + 4] = __builtin_amdgcn_mfma_f32_16x16x32_bf16(a[i], bu[j], acc[i][j + 4], 0, 0, 0);
                }
        }
    }

    // epilogue: act = silu(gate) * up, store bf16
    int rbase = lg * 4;
    #pragma unroll
    for (int i = 0; i < 4; i++) {
        #pragma unroll
        for (int rr = 0; rr < 4; rr++) {
            int m = m0 + wm * 64 + i * 16 + rbase + rr;
            if (m < mend) {
                #pragma unroll
                for (int j = 0; j < 4; j++) {
                    float gv = acc[i][j][rr];
                    float uv = acc[i][j + 4][rr];
                    float sv = gv / (1.f + __expf(-gv));
                    act[(size_t)m * I_DIM + c0 + wn * 64 + j * 16 + l15] = (bf16_t)(sv * uv);
                }
            }
        }
    }
}

// ---------------------------------------------------------------- GEMM2 (+ scale, scatter)
// Block: 128 rows x 128 out-cols, BK=64, same swizzle. 4 waves 2x2, acc[4][4],
// 32 MFMA per wave per K-step.
__global__ __launch_bounds__(256)
void gemm2_kernel(const bf16_t* __restrict__ act,
                  const float* __restrict__ w2,
                  const int* __restrict__ offsets,
                  const int* __restrict__ tile_e,
                  const int* __restrict__ tile_m0,
                  const int* __restrict__ n_slots,
                  const int* __restrict__ pair_dst,
                  const float* __restrict__ pair_wt,
                  float* __restrict__ ybuf) {
    int slot = blockIdx.x;
    if (slot >= *n_slots) return;
    int e    = tile_e[slot];
    int m0   = tile_m0[slot];
    int mend = offsets[e + 1];
    int n0   = blockIdx.y * 128;
    const float* w2e = w2 + (size_t)e * H_DIM * I_DIM;

    __shared__ __align__(16) unsigned char smem[128 * 128 * 2]; // 32 KB
    unsigned char* sA = smem;
    unsigned char* sB = smem + 128 * 128;

    int tid = threadIdx.x;
    int ar = tid >> 1, ah = tid & 1;
    bool avalid = (m0 + ar < mend);
    const bf16_t* aSrc = act + (size_t)(avalid ? (m0 + ar) : 0) * I_DIM + ah * 32;
    int aswz = ar & 7;
    const float* bSrc = w2e + (size_t)(n0 + ar) * I_DIM + ah * 32;

    int lane = tid & 63, wid = tid >> 6;
    int wm = wid >> 1, wn = wid & 1;
    int l15 = lane & 15, l7 = lane & 7, lg = lane >> 4;

    f32x4 acc[4][4];
    #pragma unroll
    for (int i = 0; i < 4; i++)
        #pragma unroll
        for (int j = 0; j < 4; j++) acc[i][j] = zero4();

    for (int k0 = 0; k0 < I_DIM; k0 += 64) {
        __syncthreads();
        {   // stage A (already bf16): 4 granules of 8 bf16
            #pragma unroll
            for (int q = 0; q < 4; q++) {
                bf16x8 v = zero8bf();
                if (avalid) v = *(const bf16x8*)(aSrc + k0 + q * 8);
                int g = ah * 4 + q;
                *(bf16x8*)(sA + ar * 128 + ((g ^ aswz) << 4)) = v;
            }
        }
        {   // stage B (w2 f32 -> bf16): 4 granules
            const f32x4* s = (const f32x4*)(bSrc + k0);
            #pragma unroll
            for (int q = 0; q < 4; q++) {
                f32x4 v0 = s[q * 2], v1 = s[q * 2 + 1];
                int g = ah * 4 + q;
                *(bf16x8*)(sB + ar * 128 + ((g ^ aswz) << 4)) = cvt8(v0, v1);
            }
        }
        __syncthreads();

        #pragma unroll
        for (int kh = 0; kh < 2; kh++) {
            int slotg = (((kh * 4 + lg) ^ l7) << 4);
            bf16x8 a[4], b[4];
            #pragma unroll
            for (int i = 0; i < 4; i++) {
                int row = wm * 64 + i * 16 + l15;
                a[i] = *(const bf16x8*)(sA + row * 128 + slotg);
            }
            #pragma unroll
            for (int j = 0; j < 4; j++) {
                int row = wn * 64 + j * 16 + l15;
                b[j] = *(const bf16x8*)(sB + row * 128 + slotg);
            }
            #pragma unroll
            for (int i = 0; i < 4; i++)
                #pragma unroll
                for (int j = 0; j < 4; j++)
                    acc[i][j] = __builtin_amdgcn_mfma_f32_16x16x32_bf16(a[i], b[j], acc[i][j], 0, 0, 0);
        }
    }

    // epilogue: scale by gate weight, scatter to ybuf[pair_dst]
    int rbase = lg * 4;
    #pragma unroll
    for (int i = 0; i < 4; i++) {
        #pragma unroll
        for (int rr = 0; rr < 4; rr++) {
            int m = m0 + wm * 64 + i * 16 + rbase + rr;
            if (m < mend) {
                int   dst = pair_dst[m];
                float w   = pair_wt[m];
                #pragma unroll
                for (int j = 0; j < 4; j++)
                    ybuf[(size_t)dst * H_DIM + n0 + wn * 64 + j * 16 + l15] = acc[i][j][rr] * w;
            }
        }
    }
}

// ---------------------------------------------------------------- combine
__global__ void combine_kernel(const float* __restrict__ ybuf,
                               float* __restrict__ out) {
    int idx = blockIdx.x * 256 + threadIdx.x;   // one float4 each
    int t = idx >> 8;                           // 256 float4 per token row
    int h = idx & 255;
    const f32x4* y0 = (const f32x4*)(ybuf + (size_t)(t * 2)     * H_DIM) + h;
    const f32x4* y1 = (const f32x4*)(ybuf + (size_t)(t * 2 + 1) * H_DIM) + h;
    f32x4 s = *y0 + *y1;
    ((f32x4*)out)[idx] = s;
}

// ---------------------------------------------------------------- launch
extern "C" void kernel_launch(void* const* d_in, const int* in_sizes, int n_in,
                              void* d_out, int out_size, void* d_ws, size_t ws_size,
                              hipStream_t stream) {
    const float* hidden = (const float*)d_in[0];
    const float* w1     = (const float*)d_in[1];
    const float* w2     = (const float*)d_in[2];
    const float* gating = (const float*)d_in[3];
    float* out = (float*)d_out;

    char* ws = (char*)d_ws;
    size_t off = 0;
    auto alloc = [&](size_t bytes) -> void* {
        void* p = ws + off;
        off += (bytes + 255) & ~(size_t)255;
        return p;
    };
    float*  ybuf       = (float*)alloc((size_t)P_MAX * H_DIM * sizeof(float));   // 16 MB
    bf16_t* act        = (bf16_t*)alloc((size_t)P_MAX * I_DIM * sizeof(bf16_t)); // 16 MB
    int*    expert_id  = (int*)alloc(P_MAX * sizeof(int));
    float*  wt         = (float*)alloc(P_MAX * sizeof(float));
    int*    pair_token = (int*)alloc(P_MAX * sizeof(int));
    int*    pair_dst   = (int*)alloc(P_MAX * sizeof(int));
    float*  pair_wt    = (float*)alloc(P_MAX * sizeof(float));
    int*    counts     = (int*)alloc(E_NUM * sizeof(int));
    int*    offsets    = (int*)alloc((E_NUM + 1) * sizeof(int));
    int*    cursor     = (int*)alloc(E_NUM * sizeof(int));
    int*    n_slots    = (int*)alloc(sizeof(int));
    int*    tile_e     = (int*)alloc(MAX_SLOTS * sizeof(int));
    int*    tile_m0    = (int*)alloc(MAX_SLOTS * sizeof(int));

    init_kernel<<<1, 64, 0, stream>>>(counts, cursor);
    router_kernel<<<(T_TOK + 255) / 256, 256, 0, stream>>>(gating, expert_id, wt, counts);
    scan_kernel<<<1, 1, 0, stream>>>(counts, offsets, tile_e, tile_m0, n_slots);
    scatter_kernel<<<(T_TOK + 255) / 256, 256, 0, stream>>>(expert_id, wt, offsets, cursor,
                                                            pair_token, pair_dst, pair_wt);
    gemm1_kernel<<<dim3(MAX_SLOTS, I_DIM / 128), 256, 0, stream>>>(
        hidden, w1, pair_token, offsets, tile_e, tile_m0, n_slots, act);
    gemm2_kernel<<<dim3(MAX_SLOTS, H_DIM / 128), 256, 0, stream>>>(
        act, w2, offsets, tile_e, tile_m0, n_slots, pair_dst, pair_wt, ybuf);
    combine_kernel<<<(T_TOK * H_DIM / 4) / 256, 256, 0, stream>>>(ybuf, out);

    (void)in_sizes; (void)n_in; (void)out_size; (void)ws_size;
}

// Round 4
// 232.430 us; speedup vs baseline: 1.5011x; 1.5011x over previous
//
#include <hip/hip_runtime.h>
#include <hip/hip_bf16.h>
#include <math.h>

// Problem constants (fixed by the reference file)
#define T_TOK 2048
#define H_DIM 1024
#define I_DIM 2048
#define E_NUM 8
#define TOPK  2
#define P_MAX (T_TOK * TOPK)   // 4096 (token, k) pairs
#define MAX_SLOTS 40           // sum_e ceil(M_e/128) <= 32 + 7 = 39

typedef __bf16 bf16_t;
typedef __attribute__((ext_vector_type(8))) __bf16 bf16x8;
typedef __attribute__((ext_vector_type(4))) float  f32x4;

// global_load_lds: per-lane GLOBAL address, wave-uniform LDS base; lane n
// writes lds_base + n*16 bytes (m104/m108). 16B width (m97: +67%).
#define GLOAD_LDS16(gptr, lptr)                                                   \
    __builtin_amdgcn_global_load_lds(                                             \
        (const __attribute__((address_space(1))) void*)(gptr),                    \
        (__attribute__((address_space(3))) void*)(lptr), 16, 0, 0)

__device__ inline f32x4 zero4() {
    f32x4 z; z[0] = 0.f; z[1] = 0.f; z[2] = 0.f; z[3] = 0.f; return z;
}

__device__ inline bf16x8 cvt8(f32x4 a, f32x4 b) {
    bf16x8 o;
    o[0] = (bf16_t)a[0]; o[1] = (bf16_t)a[1]; o[2] = (bf16_t)a[2]; o[3] = (bf16_t)a[3];
    o[4] = (bf16_t)b[0]; o[5] = (bf16_t)b[1]; o[6] = (bf16_t)b[2]; o[7] = (bf16_t)b[3];
    return o;
}

// ---------------------------------------------------------------- init
__global__ void init_kernel(int* counts, int* cursor) {
    int i = threadIdx.x;
    if (i < E_NUM) { counts[i] = 0; cursor[i] = 0; }
}

// ---------------------------------------------------------------- router
__global__ void router_kernel(const float* __restrict__ gating,
                              int* __restrict__ expert_id,
                              float* __restrict__ wt,
                              int* __restrict__ counts) {
    int t = blockIdx.x * blockDim.x + threadIdx.x;
    if (t >= T_TOK) return;
    float l[E_NUM];
    float m = -1e30f;
    #pragma unroll
    for (int e = 0; e < E_NUM; e++) { l[e] = gating[t * E_NUM + e]; m = fmaxf(m, l[e]); }
    float p[E_NUM];
    #pragma unroll
    for (int e = 0; e < E_NUM; e++) p[e] = __expf(l[e] - m);
    int i0 = 0; float p0 = p[0];
    #pragma unroll
    for (int e = 1; e < E_NUM; e++) if (p[e] > p0) { p0 = p[e]; i0 = e; }
    int i1 = -1; float p1 = -1.f;
    #pragma unroll
    for (int e = 0; e < E_NUM; e++) if (e != i0 && p[e] > p1) { p1 = p[e]; i1 = e; }
    float inv = 1.f / (p0 + p1);
    expert_id[t * 2 + 0] = i0; wt[t * 2 + 0] = p0 * inv;
    expert_id[t * 2 + 1] = i1; wt[t * 2 + 1] = p1 * inv;
    atomicAdd(&counts[i0], 1);
    atomicAdd(&counts[i1], 1);
}

// ---------------------------------------------------------------- scan + tile map
__global__ void scan_kernel(const int* __restrict__ counts,
                            int* __restrict__ offsets,
                            int* __restrict__ tile_e, int* __restrict__ tile_m0,
                            int* __restrict__ n_slots) {
    if (threadIdx.x != 0 || blockIdx.x != 0) return;
    int off = 0;
    for (int e = 0; e < E_NUM; e++) { offsets[e] = off; off += counts[e]; }
    offsets[E_NUM] = off;
    int s = 0;
    for (int e = 0; e < E_NUM; e++)
        for (int m0 = offsets[e]; m0 < offsets[e + 1]; m0 += 128) {
            tile_e[s] = e; tile_m0[s] = m0; s++;
        }
    *n_slots = s;
}

// ---------------------------------------------------------------- scatter
__global__ void scatter_kernel(const int* __restrict__ expert_id,
                               const float* __restrict__ wt,
                               const int* __restrict__ offsets,
                               int* __restrict__ cursor,
                               int* __restrict__ pair_token,
                               int* __restrict__ pair_dst,
                               float* __restrict__ pair_wt) {
    int t = blockIdx.x * blockDim.x + threadIdx.x;
    if (t >= T_TOK) return;
    #pragma unroll
    for (int k = 0; k < TOPK; k++) {
        int e = expert_id[t * 2 + k];
        int p = offsets[e] + atomicAdd(&cursor[e], 1);
        pair_token[p] = t;
        pair_dst[p]   = t * 2 + k;
        pair_wt[p]    = wt[t * 2 + k];
    }
}

// ---------------------------------------------------------------- f32 -> bf16 convert
// One pass over hidden, w1, w2. 16B loads / 16B stores per lane.
__global__ void convert_kernel(const float* __restrict__ hidden,
                               const float* __restrict__ w1,
                               const float* __restrict__ w2,
                               bf16_t* __restrict__ hbf,
                               bf16_t* __restrict__ w1bf,
                               bf16_t* __restrict__ w2bf) {
    const size_t N0 = (size_t)T_TOK * H_DIM;             // 2,097,152
    const size_t N1 = (size_t)E_NUM * 2 * I_DIM * H_DIM; // 33,554,432
    const size_t N2 = (size_t)E_NUM * H_DIM * I_DIM;     // 16,777,216
    size_t total8 = (N0 + N1 + N2) / 8;
    size_t stride = (size_t)gridDim.x * blockDim.x;
    for (size_t g = (size_t)blockIdx.x * blockDim.x + threadIdx.x; g < total8; g += stride) {
        size_t i = g * 8;
        const float* src; bf16_t* dst; size_t off;
        if (i < N0)            { src = hidden; dst = hbf;  off = i; }
        else if (i < N0 + N1)  { src = w1;     dst = w1bf; off = i - N0; }
        else                   { src = w2;     dst = w2bf; off = i - N0 - N1; }
        f32x4 a = *(const f32x4*)(src + off);
        f32x4 b = *(const f32x4*)(src + off + 4);
        *(bf16x8*)(dst + off) = cvt8(a, b);
    }
}

// ---------------------------------------------------------------- GEMM1 + SwiGLU
// m97-clone: out-tile 128 pair-rows x 64 act-cols; B-tile = 128 w1 rows
// (rows 0-63 = gate strip c0.., rows 64-127 = up strip I+c0..). BK=64.
// LDS linear 2x16KB, staged via global_load_lds(16). 4 waves 2x2:
// wave (wm,wn) = 64 rows x 32 act-cols, gate+up frags lane-aligned.
__global__ __launch_bounds__(256)
void gemm1_kernel(const bf16_t* __restrict__ hbf,
                  const bf16_t* __restrict__ w1bf,
                  const int* __restrict__ pair_token,
                  const int* __restrict__ offsets,
                  const int* __restrict__ tile_e,
                  const int* __restrict__ tile_m0,
                  const int* __restrict__ n_slots,
                  bf16_t* __restrict__ act) {
    int slot = blockIdx.x;
    if (slot >= *n_slots) return;
    int e    = tile_e[slot];
    int m0   = tile_m0[slot];
    int mend = offsets[e + 1];
    int c0   = blockIdx.y * 64;  // act cols [c0, c0+64)
    const bf16_t* w1e = w1bf + (size_t)e * (2 * I_DIM) * H_DIM;

    __shared__ __align__(16) bf16_t sA[128][64];  // 16 KB
    __shared__ __align__(16) bf16_t sB[128][64];  // 16 KB

    int tid = threadIdx.x;
    int lane = tid & 63, w = tid >> 6;
    int wm = w >> 1, wn = w & 1;
    int l15 = lane & 15, lg = lane >> 4;
    int lr = lane >> 3, lk = (lane & 7) * 8;

    // per-thread global staging addresses (k0 added in loop)
    const bf16_t* gA[4];
    const bf16_t* gB[4];
    #pragma unroll
    for (int i = 0; i < 4; i++) {
        int row = w * 32 + i * 8 + lr;
        int pr  = m0 + row;
        int tok = (pr < mend) ? pair_token[pr] : 0;   // safe dummy row
        gA[i] = hbf + (size_t)tok * H_DIM + lk;
        int w1row = (row < 64) ? (c0 + row) : (I_DIM + c0 + (row - 64));
        gB[i] = w1e + (size_t)w1row * H_DIM + lk;
    }

    f32x4 acc[4][4];  // [i][0..1]=gate, [i][2..3]=up
    #pragma unroll
    for (int i = 0; i < 4; i++)
        #pragma unroll
        for (int j = 0; j < 4; j++) acc[i][j] = zero4();

    for (int k0 = 0; k0 < H_DIM; k0 += 64) {
        __syncthreads();   // previous compute done; LDS reusable
        #pragma unroll
        for (int i = 0; i < 4; i++) GLOAD_LDS16(gA[i] + k0, &sA[w * 32 + i * 8][0]);
        #pragma unroll
        for (int i = 0; i < 4; i++) GLOAD_LDS16(gB[i] + k0, &sB[w * 32 + i * 8][0]);
        __syncthreads();   // vmcnt(0) drain -> tile ready

        #pragma unroll
        for (int kh = 0; kh < 2; kh++) {
            int koff = kh * 32 + lg * 8;
            bf16x8 a[4], bg[2], bu[2];
            #pragma unroll
            for (int i = 0; i < 4; i++)
                a[i] = *(const bf16x8*)&sA[wm * 64 + i * 16 + l15][koff];
            #pragma unroll
            for (int j = 0; j < 2; j++) {
                bg[j] = *(const bf16x8*)&sB[wn * 32 + j * 16 + l15][koff];
                bu[j] = *(const bf16x8*)&sB[64 + wn * 32 + j * 16 + l15][koff];
            }
            #pragma unroll
            for (int i = 0; i < 4; i++)
                #pragma unroll
                for (int j = 0; j < 2; j++) {
                    acc[i][j]     = __builtin_amdgcn_mfma_f32_16x16x32_bf16(a[i], bg[j], acc[i][j], 0, 0, 0);
                    acc[i][2 + j] = __builtin_amdgcn_mfma_f32_16x16x32_bf16(a[i], bu[j], acc[i][2 + j], 0, 0, 0);
                }
        }
    }

    // epilogue: act = silu(gate) * up
    #pragma unroll
    for (int i = 0; i < 4; i++) {
        #pragma unroll
        for (int rr = 0; rr < 4; rr++) {
            int m = m0 + wm * 64 + i * 16 + lg * 4 + rr;
            if (m < mend) {
                #pragma unroll
                for (int j = 0; j < 2; j++) {
                    float gv = acc[i][j][rr];
                    float uv = acc[i][2 + j][rr];
                    float sv = gv / (1.f + __expf(-gv));
                    act[(size_t)m * I_DIM + c0 + wn * 32 + j * 16 + l15] = (bf16_t)(sv * uv);
                }
            }
        }
    }
}

// ---------------------------------------------------------------- GEMM2 (+ scale, k-split)
// out-tile 128 rows x 128 cols, BK=64, K split in 2 slices of 1024 (grid.z).
// Slice z writes ybuf + z*P_MAX*H; combine sums both (deterministic).
__global__ __launch_bounds__(256)
void gemm2_kernel(const bf16_t* __restrict__ act,
                  const bf16_t* __restrict__ w2bf,
                  const int* __restrict__ offsets,
                  const int* __restrict__ tile_e,
                  const int* __restrict__ tile_m0,
                  const int* __restrict__ n_slots,
                  const int* __restrict__ pair_dst,
                  const float* __restrict__ pair_wt,
                  float* __restrict__ ybuf) {
    int slot = blockIdx.x;
    if (slot >= *n_slots) return;
    int e    = tile_e[slot];
    int m0   = tile_m0[slot];
    int mend = offsets[e + 1];
    int n0   = blockIdx.y * 128;
    int kb   = blockIdx.z * (I_DIM / 2);   // k-slice base
    const bf16_t* w2e = w2bf + (size_t)e * H_DIM * I_DIM;

    __shared__ __align__(16) bf16_t sA[128][64];
    __shared__ __align__(16) bf16_t sB[128][64];

    int tid = threadIdx.x;
    int lane = tid & 63, w = tid >> 6;
    int wm = w >> 1, wn = w & 1;
    int l15 = lane & 15, lg = lane >> 4;
    int lr = lane >> 3, lk = (lane & 7) * 8;

    const bf16_t* gA[4];
    const bf16_t* gB[4];
    #pragma unroll
    for (int i = 0; i < 4; i++) {
        int row = w * 32 + i * 8 + lr;
        // rows >= mend read neighbor data (in-arena, masked at epilogue)
        gA[i] = act + (size_t)(m0 + row) * I_DIM + kb + lk;
        gB[i] = w2e + (size_t)(n0 + row) * I_DIM + kb + lk;
    }

    f32x4 acc[4][4];
    #pragma unroll
    for (int i = 0; i < 4; i++)
        #pragma unroll
        for (int j = 0; j < 4; j++) acc[i][j] = zero4();

    for (int k0 = 0; k0 < I_DIM / 2; k0 += 64) {
        __syncthreads();
        #pragma unroll
        for (int i = 0; i < 4; i++) GLOAD_LDS16(gA[i] + k0, &sA[w * 32 + i * 8][0]);
        #pragma unroll
        for (int i = 0; i < 4; i++) GLOAD_LDS16(gB[i] + k0, &sB[w * 32 + i * 8][0]);
        __syncthreads();

        #pragma unroll
        for (int kh = 0; kh < 2; kh++) {
            int koff = kh * 32 + lg * 8;
            bf16x8 a[4], b[4];
            #pragma unroll
            for (int i = 0; i < 4; i++)
                a[i] = *(const bf16x8*)&sA[wm * 64 + i * 16 + l15][koff];
            #pragma unroll
            for (int j = 0; j < 4; j++)
                b[j] = *(const bf16x8*)&sB[wn * 64 + j * 16 + l15][koff];
            #pragma unroll
            for (int i = 0; i < 4; i++)
                #pragma unroll
                for (int j = 0; j < 4; j++)
                    acc[i][j] = __builtin_amdgcn_mfma_f32_16x16x32_bf16(a[i], b[j], acc[i][j], 0, 0, 0);
        }
    }

    float* ybufz = ybuf + (size_t)blockIdx.z * P_MAX * H_DIM;
    #pragma unroll
    for (int i = 0; i < 4; i++) {
        #pragma unroll
        for (int rr = 0; rr < 4; rr++) {
            int m = m0 + wm * 64 + i * 16 + lg * 4 + rr;
            if (m < mend) {
                int   dst = pair_dst[m];
                float wv  = pair_wt[m];
                #pragma unroll
                for (int j = 0; j < 4; j++)
                    ybufz[(size_t)dst * H_DIM + n0 + wn * 64 + j * 16 + l15] = acc[i][j][rr] * wv;
            }
        }
    }
}

// ---------------------------------------------------------------- combine
__global__ void combine_kernel(const float* __restrict__ ybuf,
                               float* __restrict__ out) {
    int idx = blockIdx.x * 256 + threadIdx.x;   // one float4 each
    int t = idx >> 8;                           // 256 float4 per token row
    int h = idx & 255;
    const size_t SL = (size_t)P_MAX * H_DIM;
    const f32x4* y00 = (const f32x4*)(ybuf + (size_t)(t * 2)     * H_DIM) + h;
    const f32x4* y01 = (const f32x4*)(ybuf + (size_t)(t * 2 + 1) * H_DIM) + h;
    const f32x4* y10 = (const f32x4*)(ybuf + SL + (size_t)(t * 2)     * H_DIM) + h;
    const f32x4* y11 = (const f32x4*)(ybuf + SL + (size_t)(t * 2 + 1) * H_DIM) + h;
    f32x4 s = (*y00 + *y10) + (*y01 + *y11);
    ((f32x4*)out)[idx] = s;
}

// ---------------------------------------------------------------- launch
extern "C" void kernel_launch(void* const* d_in, const int* in_sizes, int n_in,
                              void* d_out, int out_size, void* d_ws, size_t ws_size,
                              hipStream_t stream) {
    const float* hidden = (const float*)d_in[0];
    const float* w1     = (const float*)d_in[1];
    const float* w2     = (const float*)d_in[2];
    const float* gating = (const float*)d_in[3];
    float* out = (float*)d_out;

    char* ws = (char*)d_ws;
    size_t off = 0;
    auto alloc = [&](size_t bytes) -> void* {
        void* p = ws + off;
        off += (bytes + 255) & ~(size_t)255;
        return p;
    };
    // order matters: act must not be last (gemm2 A-staging over-reads <=508KB)
    float*  ybuf  = (float*)alloc((size_t)2 * P_MAX * H_DIM * sizeof(float));     // 33.6 MB (2 slices)
    bf16_t* act   = (bf16_t*)alloc((size_t)P_MAX * I_DIM * sizeof(bf16_t));       // 16.8 MB
    bf16_t* hbf   = (bf16_t*)alloc((size_t)T_TOK * H_DIM * sizeof(bf16_t));       //  4.2 MB
    bf16_t* w1bf  = (bf16_t*)alloc((size_t)E_NUM * 2 * I_DIM * H_DIM * sizeof(bf16_t)); // 67.1 MB
    bf16_t* w2bf  = (bf16_t*)alloc((size_t)E_NUM * H_DIM * I_DIM * sizeof(bf16_t));     // 33.6 MB
    int*    expert_id  = (int*)alloc(P_MAX * sizeof(int));
    float*  wt         = (float*)alloc(P_MAX * sizeof(float));
    int*    pair_token = (int*)alloc(P_MAX * sizeof(int));
    int*    pair_dst   = (int*)alloc(P_MAX * sizeof(int));
    float*  pair_wt    = (float*)alloc(P_MAX * sizeof(float));
    int*    counts     = (int*)alloc(E_NUM * sizeof(int));
    int*    offsets    = (int*)alloc((E_NUM + 1) * sizeof(int));
    int*    cursor     = (int*)alloc(E_NUM * sizeof(int));
    int*    n_slots    = (int*)alloc(sizeof(int));
    int*    tile_e     = (int*)alloc(MAX_SLOTS * sizeof(int));
    int*    tile_m0    = (int*)alloc(MAX_SLOTS * sizeof(int));

    init_kernel<<<1, 64, 0, stream>>>(counts, cursor);
    convert_kernel<<<2048, 256, 0, stream>>>(hidden, w1, w2, hbf, w1bf, w2bf);
    router_kernel<<<(T_TOK + 255) / 256, 256, 0, stream>>>(gating, expert_id, wt, counts);
    scan_kernel<<<1, 1, 0, stream>>>(counts, offsets, tile_e, tile_m0, n_slots);
    scatter_kernel<<<(T_TOK + 255) / 256, 256, 0, stream>>>(expert_id, wt, offsets, cursor,
                                                            pair_token, pair_dst, pair_wt);
    gemm1_kernel<<<dim3(MAX_SLOTS, I_DIM / 64), 256, 0, stream>>>(
        hbf, w1bf, pair_token, offsets, tile_e, tile_m0, n_slots, act);
    gemm2_kernel<<<dim3(MAX_SLOTS, H_DIM / 128, 2), 256, 0, stream>>>(
        act, w2bf, offsets, tile_e, tile_m0, n_slots, pair_dst, pair_wt, ybuf);
    combine_kernel<<<(T_TOK * H_DIM / 4) / 256, 256, 0, stream>>>(ybuf, out);

    (void)in_sizes; (void)n_in; (void)out_size; (void)ws_size;
}